// Round 5
// baseline (207.143 us; speedup 1.0000x reference)
//
#include <hip/hip_runtime.h>
#include <cmath>

typedef _Float16 f16;
typedef _Float16 f16x8 __attribute__((ext_vector_type(8)));
typedef _Float16 f16x4 __attribute__((ext_vector_type(4)));
typedef float    f32x4 __attribute__((ext_vector_type(4)));
typedef unsigned int u32;
typedef u32 u32x4 __attribute__((ext_vector_type(4)));

#define C_   192
#define HH   56
#define WW   56
#define NN   3136
#define BB   8
#define MM   784
#define NHEAD 4
#define HD   48
#define VT_LD 800            // padded key-dim of transposed V (784 + 16)
#define QPB  (BB*NN/64)      // 392 proj blocks, Q path
#define KVPB (BB*MM/64)      // 98 proj blocks, KV path

#define MFMA16(a,b,c) __builtin_amdgcn_mfma_f32_16x16x32_f16(a,b,c,0,0,0)

static __device__ __forceinline__ u32 pkrtz(float a, float b) {
    typedef __fp16 fp16x2 __attribute__((ext_vector_type(2)));
    fp16x2 h = __builtin_amdgcn_cvt_pkrtz(a, b);
    return __builtin_bit_cast(u32, h);
}

// ---------------------------------------------------------------------------
// Setup: blocks 0..575 = fold pointwise into projections (3 x 192 rows),
// blocks 576..703 = zero Vt pad columns m=784..799.  block = 192 threads.
__global__ __launch_bounds__(192) void setup_kernel(
    const float* __restrict__ Wq, const float* __restrict__ Wk,
    const float* __restrict__ Wv, const float* __restrict__ pw_q,
    const float* __restrict__ pw_kv,
    f16* __restrict__ Mq, f16* __restrict__ Mk, f16* __restrict__ Mv,
    f16* __restrict__ vt)
{
    int blk = blockIdx.x, tid = threadIdx.x;
    if (blk < 576) {
        int which = blk / 192, o = blk % 192;
        const float* Wm = which == 0 ? Wq : (which == 1 ? Wk : Wv);
        const float* P  = which == 0 ? pw_q : (which == 1 ? pw_kv : pw_kv + C_*C_);
        f16* Mo         = which == 0 ? Mq : (which == 1 ? Mk : Mv);
        __shared__ float wrow[C_];
        wrow[tid] = Wm[o*C_ + tid];
        __syncthreads();
        float acc = 0.f;
        #pragma unroll 8
        for (int j = 0; j < C_; ++j)
            acc = fmaf(wrow[j], P[j*C_ + tid], acc);
        Mo[o*C_ + tid] = (f16)acc;
    } else {
        int i = (blk - 576)*192 + tid;          // 24576 pad elements exactly
        int b = i / (C_*16);
        int rem = i % (C_*16);
        int c = rem / 16;
        int m = MM + (rem & 15);
        vt[((size_t)b*C_ + c)*VT_LD + m] = (f16)0.f;
    }
}

// ---------------------------------------------------------------------------
// Depthwise 3x3 + BN for both paths in one launch. fp32 compute, f16 out.
__device__ __forceinline__ void dwbn_one(
    const float* __restrict__ x, const float* __restrict__ dw,
    const float* __restrict__ gamma, const float* __restrict__ beta,
    const float* __restrict__ mean,  const float* __restrict__ var,
    f16* __restrict__ out, int OH, int OW, int stride, int idx)
{
    int c4 = idx % (C_/4);
    int sp = idx / (C_/4);
    int ox = sp % OW;
    int t2 = sp / OW;
    int oy = t2 % OH;
    int b  = t2 / OH;
    int c0 = c4*4;
    float4 acc = make_float4(0.f,0.f,0.f,0.f);
    int iy0 = oy*stride - 1;
    int ix0 = ox*stride - 1;
    #pragma unroll
    for (int ky = 0; ky < 3; ++ky) {
        int iy = iy0 + ky;
        if (iy < 0 || iy >= HH) continue;
        #pragma unroll
        for (int kx = 0; kx < 3; ++kx) {
            int ix = ix0 + kx;
            if (ix < 0 || ix >= WW) continue;
            float4 xv = *reinterpret_cast<const float4*>(
                x + ((size_t)b*NN + iy*WW + ix)*C_ + c0);
            int wi = ky*3 + kx;
            acc.x = fmaf(dw[(c0+0)*9 + wi], xv.x, acc.x);
            acc.y = fmaf(dw[(c0+1)*9 + wi], xv.y, acc.y);
            acc.z = fmaf(dw[(c0+2)*9 + wi], xv.z, acc.z);
            acc.w = fmaf(dw[(c0+3)*9 + wi], xv.w, acc.w);
        }
    }
    float i0 = gamma[c0+0]*__frsqrt_rn(var[c0+0] + 1e-5f);
    float i1 = gamma[c0+1]*__frsqrt_rn(var[c0+1] + 1e-5f);
    float i2 = gamma[c0+2]*__frsqrt_rn(var[c0+2] + 1e-5f);
    float i3 = gamma[c0+3]*__frsqrt_rn(var[c0+3] + 1e-5f);
    f16x4 r;
    r[0] = (f16)(acc.x*i0 + (beta[c0+0] - mean[c0+0]*i0));
    r[1] = (f16)(acc.y*i1 + (beta[c0+1] - mean[c0+1]*i1));
    r[2] = (f16)(acc.z*i2 + (beta[c0+2] - mean[c0+2]*i2));
    r[3] = (f16)(acc.w*i3 + (beta[c0+3] - mean[c0+3]*i3));
    *reinterpret_cast<f16x4*>(out + (size_t)idx*4) = r;
}

__global__ __launch_bounds__(256) void dwbn_both(
    const float* __restrict__ x,
    const float* __restrict__ dwq,  const float* __restrict__ gq,
    const float* __restrict__ bq_,  const float* __restrict__ mq,
    const float* __restrict__ vq,
    const float* __restrict__ dwkv, const float* __restrict__ gkv,
    const float* __restrict__ bkv,  const float* __restrict__ mkv,
    const float* __restrict__ vkv,
    f16* __restrict__ uq, f16* __restrict__ ukv)
{
    int idx = blockIdx.x*256 + threadIdx.x;
    const int totq = BB*NN*(C_/4);          // 1204224
    const int totk = BB*MM*(C_/4);          // 301056
    if (idx < totq) {
        dwbn_one(x, dwq, gq, bq_, mq, vq, uq, HH, WW, 1, idx);
    } else {
        int i2 = idx - totq;
        if (i2 < totk)
            dwbn_one(x, dwkv, gkv, bkv, mkv, vkv, ukv, 28, 28, 2, i2);
    }
}

// ---------------------------------------------------------------------------
// All projections, one launch. blocks 0..391: Q path (64 rows each).
// blocks 392..489: KV path — A-fragments loaded once, used for K and V.
__global__ __launch_bounds__(256) void proj_all(
    const f16* __restrict__ uq, const f16* __restrict__ ukv,
    const f16* __restrict__ Mq, const f16* __restrict__ Mk,
    const f16* __restrict__ Mv,
    const float* __restrict__ bq, const float* __restrict__ bk,
    const float* __restrict__ bv,
    f16* __restrict__ qb, f16* __restrict__ kb, f16* __restrict__ vt)
{
    int tid  = threadIdx.x;
    int w    = tid >> 6, l = tid & 63;
    int lrow = l & 15,  lgrp = l >> 4;
    int blk  = blockIdx.x;
    bool qpath = blk < QPB;
    const f16* U = qpath ? uq : ukv;
    int r0 = (qpath ? blk : blk - QPB)*64 + w*16;

    const f16* urow = U + (size_t)(r0 + lrow)*C_;
    f16x8 a[6];
    #pragma unroll
    for (int ch = 0; ch < 6; ++ch)
        a[ch] = *(const f16x8*)(urow + ch*32 + lgrp*8);

    if (qpath) {
        // scale = (1/sqrt(48)) * log2(e)  — attn softmax runs in exp2 domain
        const float qscale = 0.14433756729740643f * 1.4426950408889634f;
        for (int ct = 0; ct < 12; ++ct) {
            int o = ct*16 + lrow;
            const f16* mrow = Mq + (size_t)o*C_;
            f32x4 acc = {0.f,0.f,0.f,0.f};
            #pragma unroll
            for (int ch = 0; ch < 6; ++ch) {
                f16x8 bf = *(const f16x8*)(mrow + ch*32 + lgrp*8);
                acc = MFMA16(a[ch], bf, acc);
            }
            float bo = bq[o];
            #pragma unroll
            for (int i = 0; i < 4; ++i)
                qb[(size_t)(r0 + lgrp*4 + i)*C_ + o] = (f16)((acc[i] + bo)*qscale);
        }
    } else {
        for (int ct = 0; ct < 12; ++ct) {            // K projection
            int o = ct*16 + lrow;
            const f16* mrow = Mk + (size_t)o*C_;
            f32x4 acc = {0.f,0.f,0.f,0.f};
            #pragma unroll
            for (int ch = 0; ch < 6; ++ch) {
                f16x8 bf = *(const f16x8*)(mrow + ch*32 + lgrp*8);
                acc = MFMA16(a[ch], bf, acc);
            }
            float bo = bk[o];
            #pragma unroll
            for (int i = 0; i < 4; ++i)
                kb[(size_t)(r0 + lgrp*4 + i)*C_ + o] = (f16)(acc[i] + bo);
        }
        for (int ct = 0; ct < 12; ++ct) {            // V projection (transposed)
            int o = ct*16 + lrow;
            const f16* mrow = Mv + (size_t)o*C_;
            f32x4 acc = {0.f,0.f,0.f,0.f};
            #pragma unroll
            for (int ch = 0; ch < 6; ++ch) {
                f16x8 bf = *(const f16x8*)(mrow + ch*32 + lgrp*8);
                acc = MFMA16(a[ch], bf, acc);
            }
            float bo = bv[o];
            int rg = r0 + lgrp*4;
            int b  = rg / MM, m = rg % MM;            // 784 % 16 == 0, no straddle
            #pragma unroll
            for (int i = 0; i < 4; ++i)
                vt[((size_t)b*C_ + o)*VT_LD + m + i] = (f16)(acc[i] + bo);
        }
    }
}

// ---------------------------------------------------------------------------
// Flash attention, swapped-operand MFMA, zero LDS, 1 wave / 16 queries.
//
//   QK^T:  mfma(A=K, B=Q)  -> S[key=g*4+r (+16*kt)][query=lrow]
//   PV  :  mfma(A=Vt,B=P)  -> O[query=lrow][d=db*16+g*4+r]
//
// Softmax state (mrun/lrun/corr) is per-lane for query lrow — fully local.
// P redistribution (D-layout -> B-fragment) is done in registers via
// cvt_pkrtz packs + __shfl gathers (no LDS).
// XCD swizzle: blocks sharing (b,h) land on one XCD -> KV L2-resident.
__global__ __launch_bounds__(64) void attn_mfma(
    const f16* __restrict__ qb, const f16* __restrict__ kb,
    const f16* __restrict__ vt, float* __restrict__ out)
{
    int l    = threadIdx.x;
    int lrow = l & 15, g = l >> 4;
    int dec  = (blockIdx.x & 7)*784 + (blockIdx.x >> 3);   // bijective: 6272=8*784
    int qt   = dec % 196;
    int bh   = dec / 196;
    int h    = bh & 3, b = bh >> 2;
    int n0   = qt*16;

    // Q fragments (registers, whole kernel); d>=48 pad = 0 on Q side
    const f16* qrow = qb + ((size_t)b*NN + n0 + lrow)*C_ + h*HD;
    f16x8 qf0 = *(const f16x8*)(qrow + g*8);
    f16x8 qf1 = (f16x8){0,0,0,0,0,0,0,0};
    if (g < 2) qf1 = *(const f16x8*)(qrow + 32 + g*8);

    float mrun = -1e30f, lrun = 0.f;
    f32x4 o0 = {0.f,0.f,0.f,0.f}, o1 = o0, o2 = o0;

    int  la = lrow + ((g & 1) << 5);   // gather source lane A (g_src = 2*(g&1))
    int  lb = la + 16;                 // gather source lane B
    bool hi = g >= 2;                  // kt' = 2kc + (g>>1)

    for (int t = 0; t < 7; ++t) {
        int m0 = t*112;

        // ---- QK^T: S tile 112 keys x 16 queries
        f32x4 s[7];
        #pragma unroll
        for (int kt = 0; kt < 7; ++kt) {
            const f16* krow = kb + ((size_t)b*MM + m0 + kt*16 + lrow)*C_ + h*HD;
            f16x8 kf0 = *(const f16x8*)(krow + g*8);
            f16x8 kf1 = *(const f16x8*)(krow + 32 + g*8); // d>=48 junk * q0 = 0
            f32x4 acc = {0.f,0.f,0.f,0.f};
            __builtin_amdgcn_s_setprio(1);
            acc = MFMA16(kf0, qf0, acc);
            acc = MFMA16(kf1, qf1, acc);
            __builtin_amdgcn_s_setprio(0);
            s[kt] = acc;
        }

        // ---- V preload (independent of softmax -> latency hidden under it)
        const f16* vbase = vt + ((size_t)b*C_ + h*HD + lrow)*VT_LD + m0;
        f16x8 v0[4], v1[4], v2[4];
        #pragma unroll
        for (int kc = 0; kc < 4; ++kc) {
            v0[kc] = *(const f16x8*)(vbase + kc*32 + g*8);
            v1[kc] = *(const f16x8*)(vbase + 16*VT_LD + kc*32 + g*8);
            v2[kc] = *(const f16x8*)(vbase + 32*VT_LD + kc*32 + g*8);
        }

        // ---- softmax (exp2 domain), lane-local for query lrow
        float tmax = fmaxf(fmaxf(s[0][0], s[0][1]), fmaxf(s[0][2], s[0][3]));
        #pragma unroll
        for (int kt = 1; kt < 7; ++kt) {
            float tm = fmaxf(fmaxf(s[kt][0], s[kt][1]), fmaxf(s[kt][2], s[kt][3]));
            tmax = fmaxf(tmax, tm);
        }
        tmax = fmaxf(tmax, __shfl_xor(tmax, 16));
        tmax = fmaxf(tmax, __shfl_xor(tmax, 32));
        float mnew = fmaxf(mrun, tmax);
        float corr = exp2f(mrun - mnew);
        mrun = mnew;
        float psum = 0.f;
        #pragma unroll
        for (int kt = 0; kt < 7; ++kt) {
            #pragma unroll
            for (int r = 0; r < 4; ++r) {
                float p = exp2f(s[kt][r] - mnew);
                s[kt][r] = p;
                psum += p;
            }
        }
        psum += __shfl_xor(psum, 16);
        psum += __shfl_xor(psum, 32);
        lrun = lrun*corr + psum;

        // ---- pack P to f16 pairs:  pk0 = keys (g*4+0, g*4+1), pk1 = (+2,+3)
        u32 pk0[7], pk1[7];
        #pragma unroll
        for (int kt = 0; kt < 7; ++kt) {
            pk0[kt] = pkrtz(s[kt][0], s[kt][1]);
            pk1[kt] = pkrtz(s[kt][2], s[kt][3]);
        }

        // ---- rescale O
        #pragma unroll
        for (int r = 0; r < 4; ++r) {
            o0[r] *= corr; o1[r] *= corr; o2[r] *= corr;
        }

        // ---- PV per 32-key chunk: gather P B-frag in registers, 3 MFMAs
        #pragma unroll
        for (int kc = 0; kc < 4; ++kc) {
            u32 w0, w1, w2, w3;
            if (kc < 3) {
                u32 a0  = __shfl(pk0[2*kc],   la);
                u32 a0h = __shfl(pk0[2*kc+1], la);
                u32 a1  = __shfl(pk1[2*kc],   la);
                u32 a1h = __shfl(pk1[2*kc+1], la);
                u32 b0  = __shfl(pk0[2*kc],   lb);
                u32 b0h = __shfl(pk0[2*kc+1], lb);
                u32 b1  = __shfl(pk1[2*kc],   lb);
                u32 b1h = __shfl(pk1[2*kc+1], lb);
                w0 = hi ? a0h : a0;  w1 = hi ? a1h : a1;
                w2 = hi ? b0h : b0;  w3 = hi ? b1h : b1;
            } else {   // keys 96..111 real (kt=6); 112..127 pad -> zero P
                u32 a0 = __shfl(pk0[6], la);
                u32 a1 = __shfl(pk1[6], la);
                u32 b0 = __shfl(pk0[6], lb);
                u32 b1 = __shfl(pk1[6], lb);
                w0 = hi ? 0u : a0;  w1 = hi ? 0u : a1;
                w2 = hi ? 0u : b0;  w3 = hi ? 0u : b1;
            }
            u32x4 uw = {w0, w1, w2, w3};
            f16x8 pb = __builtin_bit_cast(f16x8, uw);
            __builtin_amdgcn_s_setprio(1);
            o0 = MFMA16(v0[kc], pb, o0);
            o1 = MFMA16(v1[kc], pb, o1);
            o2 = MFMA16(v2[kc], pb, o2);
            __builtin_amdgcn_s_setprio(0);
        }
    }

    // ---- epilogue: all lane-local; float4 stores
    float inv = 1.f / lrun;
    f32x4 r0, r1, r2;
    #pragma unroll
    for (int r = 0; r < 4; ++r) {
        r0[r] = o0[r]*inv; r1[r] = o1[r]*inv; r2[r] = o2[r]*inv;
    }
    float* obase = out + ((size_t)b*NN + n0 + lrow)*C_ + h*HD + g*4;
    *(f32x4*)(obase)      = r0;
    *(f32x4*)(obase + 16) = r1;
    *(f32x4*)(obase + 32) = r2;
}

// ---------------------------------------------------------------------------
extern "C" void kernel_launch(void* const* d_in, const int* in_sizes, int n_in,
                              void* d_out, int out_size, void* d_ws, size_t ws_size,
                              hipStream_t stream)
{
    const float* x     = (const float*)d_in[0];
    const float* dw_q  = (const float*)d_in[3];
    const float* bnqg  = (const float*)d_in[4];
    const float* bnqb  = (const float*)d_in[5];
    const float* bnqm  = (const float*)d_in[6];
    const float* bnqv  = (const float*)d_in[7];
    const float* pw_q  = (const float*)d_in[8];
    const float* dw_kv = (const float*)d_in[9];
    const float* bnkg  = (const float*)d_in[10];
    const float* bnkb  = (const float*)d_in[11];
    const float* bnkm  = (const float*)d_in[12];
    const float* bnkvv = (const float*)d_in[13];
    const float* pw_kv = (const float*)d_in[14];
    const float* Wq    = (const float*)d_in[15];
    const float* bq    = (const float*)d_in[16];
    const float* Wk    = (const float*)d_in[17];
    const float* bk    = (const float*)d_in[18];
    const float* Wv    = (const float*)d_in[19];
    const float* bv    = (const float*)d_in[20];
    float* out = (float*)d_out;

    f16* p   = (f16*)d_ws;
    f16* Mq16  = p;  p += C_*C_;
    f16* Mk16  = p;  p += C_*C_;
    f16* Mv16  = p;  p += C_*C_;
    f16* uq16  = p;  p += (size_t)BB*NN*C_;
    f16* ukv16 = p;  p += (size_t)BB*MM*C_;
    f16* qb16  = p;  p += (size_t)BB*NN*C_ + 256;   // pad: frag tail reads
    f16* kb16  = p;  p += (size_t)BB*MM*C_ + 256;   // pad: frag tail reads
    f16* vt16  = p;  p += (size_t)BB*C_*VT_LD;

    setup_kernel<<<704, 192, 0, stream>>>(
        Wq, Wk, Wv, pw_q, pw_kv, Mq16, Mk16, Mv16, vt16);

    dwbn_both<<<5880, 256, 0, stream>>>(
        x, dw_q, bnqg, bnqb, bnqm, bnqv,
        dw_kv, bnkg, bnkb, bnkm, bnkvv, uq16, ukv16);

    proj_all<<<QPB + KVPB, 256, 0, stream>>>(
        uq16, ukv16, Mq16, Mk16, Mv16, bq, bk, bv, qb16, kb16, vt16);

    attn_mfma<<<BB*NHEAD*(NN/16), 64, 0, stream>>>(qb16, kb16, vt16, out);
}

// Round 7
// 205.762 us; speedup vs baseline: 1.0067x; 1.0067x over previous
//
#include <hip/hip_runtime.h>
#include <cmath>

typedef _Float16 f16;
typedef _Float16 f16x8 __attribute__((ext_vector_type(8)));
typedef _Float16 f16x4 __attribute__((ext_vector_type(4)));
typedef float    f32x4 __attribute__((ext_vector_type(4)));
typedef unsigned int u32;
typedef u32 u32x4 __attribute__((ext_vector_type(4)));

#define C_   192
#define HH   56
#define WW   56
#define NN   3136
#define BB   8
#define MM   784
#define NHEAD 4
#define HD   48
#define VT_LD 800            // padded key-dim of transposed V (784 + 16)
#define QPB  (BB*NN/64)      // 392 proj blocks, Q path
#define KVPB (BB*MM/64)      // 98 proj blocks, KV path

#define MFMA16(a,b,c) __builtin_amdgcn_mfma_f32_16x16x32_f16(a,b,c,0,0,0)

static __device__ __forceinline__ u32 pkrtz(float a, float b) {
    typedef __fp16 fp16x2 __attribute__((ext_vector_type(2)));
    fp16x2 h = __builtin_amdgcn_cvt_pkrtz(a, b);
    return __builtin_bit_cast(u32, h);
}

// ---------------------------------------------------------------------------
// Setup: blocks 0..575 = fold pointwise into projections (3 x 192 rows),
// blocks 576..703 = zero Vt pad columns m=784..799.  block = 192 threads.
__global__ __launch_bounds__(192) void setup_kernel(
    const float* __restrict__ Wq, const float* __restrict__ Wk,
    const float* __restrict__ Wv, const float* __restrict__ pw_q,
    const float* __restrict__ pw_kv,
    f16* __restrict__ Mq, f16* __restrict__ Mk, f16* __restrict__ Mv,
    f16* __restrict__ vt)
{
    int blk = blockIdx.x, tid = threadIdx.x;
    if (blk < 576) {
        int which = blk / 192, o = blk % 192;
        const float* Wm = which == 0 ? Wq : (which == 1 ? Wk : Wv);
        const float* P  = which == 0 ? pw_q : (which == 1 ? pw_kv : pw_kv + C_*C_);
        f16* Mo         = which == 0 ? Mq : (which == 1 ? Mk : Mv);
        __shared__ float wrow[C_];
        wrow[tid] = Wm[o*C_ + tid];
        __syncthreads();
        float acc = 0.f;
        #pragma unroll 8
        for (int j = 0; j < C_; ++j)
            acc = fmaf(wrow[j], P[j*C_ + tid], acc);
        Mo[o*C_ + tid] = (f16)acc;
    } else {
        int i = (blk - 576)*192 + tid;          // 24576 pad elements exactly
        int b = i / (C_*16);
        int rem = i % (C_*16);
        int c = rem / 16;
        int m = MM + (rem & 15);
        vt[((size_t)b*C_ + c)*VT_LD + m] = (f16)0.f;
    }
}

// ---------------------------------------------------------------------------
// Depthwise 3x3 + BN for both paths in one launch. fp32 compute, f16 out.
__device__ __forceinline__ void dwbn_one(
    const float* __restrict__ x, const float* __restrict__ dw,
    const float* __restrict__ gamma, const float* __restrict__ beta,
    const float* __restrict__ mean,  const float* __restrict__ var,
    f16* __restrict__ out, int OH, int OW, int stride, int idx)
{
    int c4 = idx % (C_/4);
    int sp = idx / (C_/4);
    int ox = sp % OW;
    int t2 = sp / OW;
    int oy = t2 % OH;
    int b  = t2 / OH;
    int c0 = c4*4;
    float4 acc = make_float4(0.f,0.f,0.f,0.f);
    int iy0 = oy*stride - 1;
    int ix0 = ox*stride - 1;
    #pragma unroll
    for (int ky = 0; ky < 3; ++ky) {
        int iy = iy0 + ky;
        if (iy < 0 || iy >= HH) continue;
        #pragma unroll
        for (int kx = 0; kx < 3; ++kx) {
            int ix = ix0 + kx;
            if (ix < 0 || ix >= WW) continue;
            float4 xv = *reinterpret_cast<const float4*>(
                x + ((size_t)b*NN + iy*WW + ix)*C_ + c0);
            int wi = ky*3 + kx;
            acc.x = fmaf(dw[(c0+0)*9 + wi], xv.x, acc.x);
            acc.y = fmaf(dw[(c0+1)*9 + wi], xv.y, acc.y);
            acc.z = fmaf(dw[(c0+2)*9 + wi], xv.z, acc.z);
            acc.w = fmaf(dw[(c0+3)*9 + wi], xv.w, acc.w);
        }
    }
    float i0 = gamma[c0+0]*__frsqrt_rn(var[c0+0] + 1e-5f);
    float i1 = gamma[c0+1]*__frsqrt_rn(var[c0+1] + 1e-5f);
    float i2 = gamma[c0+2]*__frsqrt_rn(var[c0+2] + 1e-5f);
    float i3 = gamma[c0+3]*__frsqrt_rn(var[c0+3] + 1e-5f);
    f16x4 r;
    r[0] = (f16)(acc.x*i0 + (beta[c0+0] - mean[c0+0]*i0));
    r[1] = (f16)(acc.y*i1 + (beta[c0+1] - mean[c0+1]*i1));
    r[2] = (f16)(acc.z*i2 + (beta[c0+2] - mean[c0+2]*i2));
    r[3] = (f16)(acc.w*i3 + (beta[c0+3] - mean[c0+3]*i3));
    *reinterpret_cast<f16x4*>(out + (size_t)idx*4) = r;
}

__global__ __launch_bounds__(256) void dwbn_both(
    const float* __restrict__ x,
    const float* __restrict__ dwq,  const float* __restrict__ gq,
    const float* __restrict__ bq_,  const float* __restrict__ mq,
    const float* __restrict__ vq,
    const float* __restrict__ dwkv, const float* __restrict__ gkv,
    const float* __restrict__ bkv,  const float* __restrict__ mkv,
    const float* __restrict__ vkv,
    f16* __restrict__ uq, f16* __restrict__ ukv)
{
    int idx = blockIdx.x*256 + threadIdx.x;
    const int totq = BB*NN*(C_/4);          // 1204224
    const int totk = BB*MM*(C_/4);          // 301056
    if (idx < totq) {
        dwbn_one(x, dwq, gq, bq_, mq, vq, uq, HH, WW, 1, idx);
    } else {
        int i2 = idx - totq;
        if (i2 < totk)
            dwbn_one(x, dwkv, gkv, bkv, mkv, vkv, ukv, 28, 28, 2, i2);
    }
}

// ---------------------------------------------------------------------------
// All projections, one launch. blocks 0..391: Q path (64 rows each).
// blocks 392..489: KV path — A-fragments loaded once, used for K and V.
// Ping-pong prefetch of B-fragments across the 12 column-tiles.
__global__ __launch_bounds__(256, 1) void proj_all(
    const f16* __restrict__ uq, const f16* __restrict__ ukv,
    const f16* __restrict__ Mq, const f16* __restrict__ Mk,
    const f16* __restrict__ Mv,
    const float* __restrict__ bq, const float* __restrict__ bk,
    const float* __restrict__ bv,
    f16* __restrict__ qb, f16* __restrict__ kb, f16* __restrict__ vt)
{
    int tid  = threadIdx.x;
    int w    = tid >> 6, l = tid & 63;
    int lrow = l & 15,  lgrp = l >> 4;
    int blk  = blockIdx.x;
    bool qpath = blk < QPB;
    const f16* U = qpath ? uq : ukv;
    int r0 = (qpath ? blk : blk - QPB)*64 + w*16;

    const f16* urow = U + (size_t)(r0 + lrow)*C_;
    f16x8 a[6];
    #pragma unroll
    for (int ch = 0; ch < 6; ++ch)
        a[ch] = *(const f16x8*)(urow + ch*32 + lgrp*8);

    f16x8 bfA[6], bfB[6];

    if (qpath) {
        // scale = (1/sqrt(48)) * log2(e)  — attn softmax runs in exp2 domain
        const float qscale = 0.14433756729740643f * 1.4426950408889634f;
        #pragma unroll
        for (int ch = 0; ch < 6; ++ch)
            bfA[ch] = *(const f16x8*)(Mq + (size_t)lrow*C_ + ch*32 + lgrp*8);
        #pragma unroll
        for (int ct = 0; ct < 12; ++ct) {
            f16x8* cur = (ct & 1) ? bfB : bfA;
            f16x8* nxt = (ct & 1) ? bfA : bfB;
            if (ct < 11) {
                const f16* mrow = Mq + (size_t)((ct+1)*16 + lrow)*C_;
                #pragma unroll
                for (int ch = 0; ch < 6; ++ch)
                    nxt[ch] = *(const f16x8*)(mrow + ch*32 + lgrp*8);
            }
            int o = ct*16 + lrow;
            f32x4 acc = {0.f,0.f,0.f,0.f};
            #pragma unroll
            for (int ch = 0; ch < 6; ++ch)
                acc = MFMA16(a[ch], cur[ch], acc);
            float bo = bq[o];
            #pragma unroll
            for (int i = 0; i < 4; ++i)
                qb[(size_t)(r0 + lgrp*4 + i)*C_ + o] = (f16)((acc[i] + bo)*qscale);
        }
    } else {
        #pragma unroll
        for (int ch = 0; ch < 6; ++ch)
            bfA[ch] = *(const f16x8*)(Mk + (size_t)lrow*C_ + ch*32 + lgrp*8);
        #pragma unroll
        for (int ct = 0; ct < 12; ++ct) {            // K projection
            f16x8* cur = (ct & 1) ? bfB : bfA;
            f16x8* nxt = (ct & 1) ? bfA : bfB;
            const f16* nrow = (ct < 11) ? Mk + (size_t)((ct+1)*16 + lrow)*C_
                                        : Mv + (size_t)lrow*C_;
            #pragma unroll
            for (int ch = 0; ch < 6; ++ch)
                nxt[ch] = *(const f16x8*)(nrow + ch*32 + lgrp*8);
            int o = ct*16 + lrow;
            f32x4 acc = {0.f,0.f,0.f,0.f};
            #pragma unroll
            for (int ch = 0; ch < 6; ++ch)
                acc = MFMA16(a[ch], cur[ch], acc);
            float bo = bk[o];
            #pragma unroll
            for (int i = 0; i < 4; ++i)
                kb[(size_t)(r0 + lgrp*4 + i)*C_ + o] = (f16)(acc[i] + bo);
        }
        // V: K-loop's last prefetch (ct=11, odd) put Mv tile 0 into bfA,
        // so the V loop uses the SAME parity as the K loop (even ct -> bfA).
        #pragma unroll
        for (int ct = 0; ct < 12; ++ct) {            // V projection (transposed)
            f16x8* cur = (ct & 1) ? bfB : bfA;
            f16x8* nxt = (ct & 1) ? bfA : bfB;
            if (ct < 11) {
                const f16* mrow = Mv + (size_t)((ct+1)*16 + lrow)*C_;
                #pragma unroll
                for (int ch = 0; ch < 6; ++ch)
                    nxt[ch] = *(const f16x8*)(mrow + ch*32 + lgrp*8);
            }
            int o = ct*16 + lrow;
            f32x4 acc = {0.f,0.f,0.f,0.f};
            #pragma unroll
            for (int ch = 0; ch < 6; ++ch)
                acc = MFMA16(a[ch], cur[ch], acc);
            float bo = bv[o];
            int rg = r0 + lgrp*4;
            int b  = rg / MM, m = rg % MM;            // 784 % 16 == 0, no straddle
            #pragma unroll
            for (int i = 0; i < 4; ++i)
                vt[((size_t)b*C_ + o)*VT_LD + m + i] = (f16)(acc[i] + bo);
        }
    }
}

// ---------------------------------------------------------------------------
// Flash attention, swapped-operand MFMA, zero LDS, 1 wave / 16 queries.
// __launch_bounds__(64,1): let the compiler use a big VGPR budget so the
// K-tile for t+1 (56 VGPRs) and V-tile for t (48 VGPRs) stay IN FLIGHT —
// R5 ran at 68 VGPRs and serialized every load (~120us invariant).
__global__ __launch_bounds__(64, 1) void attn_mfma(
    const f16* __restrict__ qb, const f16* __restrict__ kb,
    const f16* __restrict__ vt, float* __restrict__ out)
{
    int l    = threadIdx.x;
    int lrow = l & 15, g = l >> 4;
    int dec  = (blockIdx.x & 7)*784 + (blockIdx.x >> 3);   // bijective: 6272=8*784
    int qt   = dec % 196;
    int bh   = dec / 196;
    int h    = bh & 3, b = bh >> 2;
    int n0   = qt*16;

    // Q fragments (registers, whole kernel); d>=48 pad = 0 on Q side
    const f16* qrow = qb + ((size_t)b*NN + n0 + lrow)*C_ + h*HD;
    f16x8 qf0 = *(const f16x8*)(qrow + g*8);
    f16x8 qf1 = (f16x8){0,0,0,0,0,0,0,0};
    if (g < 2) qf1 = *(const f16x8*)(qrow + 32 + g*8);

    float mrun = -1e30f, lrun = 0.f;
    f32x4 o0 = {0.f,0.f,0.f,0.f}, o1 = o0, o2 = o0;

    int  la = lrow + ((g & 1) << 5);   // gather source lane A (g_src = 2*(g&1))
    int  lb = la + 16;                 // gather source lane B
    bool hi = g >= 2;                  // kt' = 2kc + (g>>1)

    const f16* kbb = kb + (size_t)b*MM*C_ + h*HD;

    // ping-pong K-tile register buffers (each 7 x 2 x f16x8 = 56 VGPRs)
    f16x8 kA0[7], kA1[7], kB0[7], kB1[7];

    // prologue: K tile 0
    #pragma unroll
    for (int kt = 0; kt < 7; ++kt) {
        const f16* krow = kbb + (size_t)(kt*16 + lrow)*C_;
        kA0[kt] = *(const f16x8*)(krow + g*8);
        kA1[kt] = *(const f16x8*)(krow + 32 + g*8);  // d>=48 junk * q0 = 0
    }

    #pragma unroll
    for (int t = 0; t < 7; ++t) {
        int m0 = t*112;
        f16x8* k0 = (t & 1) ? kB0 : kA0;
        f16x8* k1 = (t & 1) ? kB1 : kA1;
        f16x8* n0_ = (t & 1) ? kA0 : kB0;
        f16x8* n1_ = (t & 1) ? kA1 : kB1;

        // ---- V preload for this tile (needed only after softmax)
        const f16* vbase = vt + ((size_t)b*C_ + h*HD + lrow)*VT_LD + m0;
        f16x8 v0[4], v1[4], v2[4];
        #pragma unroll
        for (int kc = 0; kc < 4; ++kc) {
            v0[kc] = *(const f16x8*)(vbase + kc*32 + g*8);
            v1[kc] = *(const f16x8*)(vbase + 16*VT_LD + kc*32 + g*8);
            v2[kc] = *(const f16x8*)(vbase + 32*VT_LD + kc*32 + g*8);
        }

        // ---- QK^T from prefetched K: S tile 112 keys x 16 queries
        f32x4 s[7];
        #pragma unroll
        for (int kt = 0; kt < 7; ++kt) {
            f32x4 acc = {0.f,0.f,0.f,0.f};
            __builtin_amdgcn_s_setprio(1);
            acc = MFMA16(k0[kt], qf0, acc);
            acc = MFMA16(k1[kt], qf1, acc);
            __builtin_amdgcn_s_setprio(0);
            s[kt] = acc;
        }

        // ---- prefetch K tile t+1 (latency hides under softmax + PV)
        if (t < 6) {
            #pragma unroll
            for (int kt = 0; kt < 7; ++kt) {
                const f16* krow = kbb + (size_t)(m0 + 112 + kt*16 + lrow)*C_;
                n0_[kt] = *(const f16x8*)(krow + g*8);
                n1_[kt] = *(const f16x8*)(krow + 32 + g*8);
            }
        }

        // ---- softmax (exp2 domain), lane-local for query lrow
        float tmax = fmaxf(fmaxf(s[0][0], s[0][1]), fmaxf(s[0][2], s[0][3]));
        #pragma unroll
        for (int kt = 1; kt < 7; ++kt) {
            float tm = fmaxf(fmaxf(s[kt][0], s[kt][1]), fmaxf(s[kt][2], s[kt][3]));
            tmax = fmaxf(tmax, tm);
        }
        tmax = fmaxf(tmax, __shfl_xor(tmax, 16));
        tmax = fmaxf(tmax, __shfl_xor(tmax, 32));
        float mnew = fmaxf(mrun, tmax);
        float corr = exp2f(mrun - mnew);
        mrun = mnew;
        float psum = 0.f;
        #pragma unroll
        for (int kt = 0; kt < 7; ++kt) {
            #pragma unroll
            for (int r = 0; r < 4; ++r) {
                float p = exp2f(s[kt][r] - mnew);
                s[kt][r] = p;
                psum += p;
            }
        }
        psum += __shfl_xor(psum, 16);
        psum += __shfl_xor(psum, 32);
        lrun = lrun*corr + psum;

        // ---- pack P to f16 pairs:  pk0 = keys (g*4+0, g*4+1), pk1 = (+2,+3)
        u32 pk0[7], pk1[7];
        #pragma unroll
        for (int kt = 0; kt < 7; ++kt) {
            pk0[kt] = pkrtz(s[kt][0], s[kt][1]);
            pk1[kt] = pkrtz(s[kt][2], s[kt][3]);
        }

        // ---- rescale O
        #pragma unroll
        for (int r = 0; r < 4; ++r) {
            o0[r] *= corr; o1[r] *= corr; o2[r] *= corr;
        }

        // ---- PV per 32-key chunk: gather P B-frag in registers, 3 MFMAs
        #pragma unroll
        for (int kc = 0; kc < 4; ++kc) {
            u32 w0, w1, w2, w3;
            if (kc < 3) {
                u32 a0  = __shfl(pk0[2*kc],   la);
                u32 a0h = __shfl(pk0[2*kc+1], la);
                u32 a1  = __shfl(pk1[2*kc],   la);
                u32 a1h = __shfl(pk1[2*kc+1], la);
                u32 b0  = __shfl(pk0[2*kc],   lb);
                u32 b0h = __shfl(pk0[2*kc+1], lb);
                u32 b1  = __shfl(pk1[2*kc],   lb);
                u32 b1h = __shfl(pk1[2*kc+1], lb);
                w0 = hi ? a0h : a0;  w1 = hi ? a1h : a1;
                w2 = hi ? b0h : b0;  w3 = hi ? b1h : b1;
            } else {   // keys 96..111 real (kt=6); 112..127 pad -> zero P
                u32 a0 = __shfl(pk0[6], la);
                u32 a1 = __shfl(pk1[6], la);
                u32 b0 = __shfl(pk0[6], lb);
                u32 b1 = __shfl(pk1[6], lb);
                w0 = hi ? 0u : a0;  w1 = hi ? 0u : a1;
                w2 = hi ? 0u : b0;  w3 = hi ? 0u : b1;
            }
            u32x4 uw = {w0, w1, w2, w3};
            f16x8 pb = __builtin_bit_cast(f16x8, uw);
            __builtin_amdgcn_s_setprio(1);
            o0 = MFMA16(v0[kc], pb, o0);
            o1 = MFMA16(v1[kc], pb, o1);
            o2 = MFMA16(v2[kc], pb, o2);
            __builtin_amdgcn_s_setprio(0);
        }
    }

    // ---- epilogue: all lane-local; float4 stores
    float inv = 1.f / lrun;
    f32x4 r0, r1, r2;
    #pragma unroll
    for (int r = 0; r < 4; ++r) {
        r0[r] = o0[r]*inv; r1[r] = o1[r]*inv; r2[r] = o2[r]*inv;
    }
    float* obase = out + ((size_t)b*NN + n0 + lrow)*C_ + h*HD + g*4;
    *(f32x4*)(obase)      = r0;
    *(f32x4*)(obase + 16) = r1;
    *(f32x4*)(obase + 32) = r2;
}

// ---------------------------------------------------------------------------
extern "C" void kernel_launch(void* const* d_in, const int* in_sizes, int n_in,
                              void* d_out, int out_size, void* d_ws, size_t ws_size,
                              hipStream_t stream)
{
    const float* x     = (const float*)d_in[0];
    const float* dw_q  = (const float*)d_in[3];
    const float* bnqg  = (const float*)d_in[4];
    const float* bnqb  = (const float*)d_in[5];
    const float* bnqm  = (const float*)d_in[6];
    const float* bnqv  = (const float*)d_in[7];
    const float* pw_q  = (const float*)d_in[8];
    const float* dw_kv = (const float*)d_in[9];
    const float* bnkg  = (const float*)d_in[10];
    const float* bnkb  = (const float*)d_in[11];
    const float* bnkm  = (const float*)d_in[12];
    const float* bnkvv = (const float*)d_in[13];
    const float* pw_kv = (const float*)d_in[14];
    const float* Wq    = (const float*)d_in[15];
    const float* bq    = (const float*)d_in[16];
    const float* Wk    = (const float*)d_in[17];
    const float* bk    = (const float*)d_in[18];
    const float* Wv    = (const float*)d_in[19];
    const float* bv    = (const float*)d_in[20];
    float* out = (float*)d_out;

    f16* p   = (f16*)d_ws;
    f16* Mq16  = p;  p += C_*C_;
    f16* Mk16  = p;  p += C_*C_;
    f16* Mv16  = p;  p += C_*C_;
    f16* uq16  = p;  p += (size_t)BB*NN*C_;
    f16* ukv16 = p;  p += (size_t)BB*MM*C_;
    f16* qb16  = p;  p += (size_t)BB*NN*C_ + 256;   // pad: frag tail reads
    f16* kb16  = p;  p += (size_t)BB*MM*C_ + 256;   // pad: frag tail reads
    f16* vt16  = p;  p += (size_t)BB*C_*VT_LD;

    setup_kernel<<<704, 192, 0, stream>>>(
        Wq, Wk, Wv, pw_q, pw_kv, Mq16, Mk16, Mv16, vt16);

    dwbn_both<<<5880, 256, 0, stream>>>(
        x, dw_q, bnqg, bnqb, bnqm, bnqv,
        dw_kv, bnkg, bnkb, bnkm, bnkvv, uq16, ukv16);

    proj_all<<<QPB + KVPB, 256, 0, stream>>>(
        uq16, ukv16, Mq16, Mk16, Mv16, bq, bk, bv, qb16, kb16, vt16);

    attn_mfma<<<BB*NHEAD*(NN/16), 64, 0, stream>>>(qb16, kb16, vt16, out);
}